// Round 2
// baseline (7020.752 us; speedup 1.0000x reference)
//
#include <hip/hip_runtime.h>
#include <hip/hip_bf16.h>

typedef unsigned short u16;
typedef __attribute__((ext_vector_type(8))) short bf16x8;
typedef __attribute__((ext_vector_type(4))) float f32x4;

#define N_NODES 50000
#define EDGES 500000
#define WPT 31250   // waves per edge type (EDGES/16)

__device__ __forceinline__ u16 f2bf(float f) {
  return __builtin_bit_cast(u16, __float2bfloat16(f));
}
__device__ __forceinline__ float bf2f(u16 u) {
  return __builtin_bit_cast(float, ((unsigned)u) << 16);
}
__device__ __forceinline__ float bfe(bf16x8 v, int j) {
  return bf2f((u16)v[j]);
}

// ---------------------------------------------------------------------------
// weights -> bf16 tables (9 x 128x128 row-major)
// 0 Wp, 1 Wc, 2 W1a, 3 W1b, 4 W1c, 5 Wrel_ab, 6 Wroot_ab, 7 Wrel_ba, 8 Wroot_ba
// ---------------------------------------------------------------------------
__global__ __launch_bounds__(256) void prep_weights(
    const float* __restrict__ Wp, const float* __restrict__ Wc,
    const float* __restrict__ W1,
    const float* __restrict__ Wrel_ab, const float* __restrict__ Wroot_ab,
    const float* __restrict__ Wrel_ba, const float* __restrict__ Wroot_ba,
    u16* __restrict__ out)
{
  int tid = blockIdx.x * 256 + threadIdx.x;  // 9*16384
  int m = tid >> 14;
  int idx = tid & 16383;
  int r = idx >> 7;
  int c = idx & 127;
  float val;
  switch (m) {
    case 0: val = Wp[r * 128 + c]; break;
    case 1: val = Wc[r * 128 + c]; break;
    case 2: val = W1[r * 384 + c]; break;
    case 3: val = W1[r * 384 + 128 + c]; break;
    case 4: val = W1[r * 384 + 256 + c]; break;
    case 5: val = Wrel_ab[r * 128 + c]; break;
    case 6: val = Wroot_ab[r * 128 + c]; break;
    case 7: val = Wrel_ba[r * 128 + c]; break;
    default: val = Wroot_ba[r * 128 + c]; break;
  }
  out[tid] = f2bf(val);
}

// ---------------------------------------------------------------------------
// x (fp32) -> bf16 tables, 8 elems/thread
// ---------------------------------------------------------------------------
__global__ __launch_bounds__(256) void cast_x(
    const float* __restrict__ xa, const float* __restrict__ xb,
    u16* __restrict__ oa, u16* __restrict__ ob)
{
  int t = blockIdx.x * 256 + threadIdx.x;    // 1,600,000 threads
  const int HALF = (N_NODES * 128) / 8;      // 800,000
  const float* src;
  u16* dst;
  int idx;
  if (t < HALF) { src = xa; dst = oa; idx = t * 8; }
  else          { src = xb; dst = ob; idx = (t - HALF) * 8; }
  f32x4 a = *(const f32x4*)(src + idx);
  f32x4 b = *(const f32x4*)(src + idx + 4);
  bf16x8 o;
#pragma unroll
  for (int j = 0; j < 4; j++) {
    o[j]     = (short)f2bf(a[j]);
    o[j + 4] = (short)f2bf(b[j]);
  }
  *(bf16x8*)(dst + idx) = o;
}

// ---------------------------------------------------------------------------
// Fused encoder: per node set computes
//   u = lrelu(x@Wp^T+bp) @ W1a^T + b1   (b1 folded in!)
//   v = lrelu(x@Wc^T+bc) @ W1b^T
// One wave = 16 rows; intermediate transposed C-layout -> A-layout via LDS.
// ---------------------------------------------------------------------------
__global__ __launch_bounds__(256) void encoder(
    const u16* __restrict__ xbf,
    const u16* __restrict__ Wp_b, const float* __restrict__ bp,
    const u16* __restrict__ Wc_b, const float* __restrict__ bc,
    const u16* __restrict__ W1a_b, const float* __restrict__ b1,
    const u16* __restrict__ W1b_b,
    u16* __restrict__ u_out, u16* __restrict__ v_out)
{
  __shared__ u16 tile[4][2176];   // 16 rows x pitch 136 bf16, per wave
  int widx = threadIdx.x >> 6;
  int wave = blockIdx.x * 4 + widx;
  if (wave > (N_NODES / 16 - 1)) wave = N_NODES / 16 - 1;  // clamp: dup work, all reach barriers
  int row0 = wave * 16;
  int lane = threadIdx.x & 63;
  int col = lane & 15;
  int quad = lane >> 4;
  u16* tl = tile[widx];

  bf16x8 af[4];
#pragma unroll
  for (int ks = 0; ks < 4; ks++)
    af[ks] = *(const bf16x8*)(xbf + (size_t)(row0 + col) * 128 + ks * 32 + quad * 8);

  f32x4 zero = {0.f, 0.f, 0.f, 0.f};

  for (int chain = 0; chain < 2; chain++) {
    const u16* Wenc = chain ? Wc_b : Wp_b;
    const float* benc = chain ? bc : bp;
    const u16* Wmix = chain ? W1b_b : W1a_b;
    const float* bmix = chain ? nullptr : b1;
    u16* outp = chain ? v_out : u_out;

    f32x4 acc[8];
#pragma unroll
    for (int nt = 0; nt < 8; nt++) acc[nt] = zero;
#pragma unroll
    for (int ks = 0; ks < 4; ks++) {
      const u16* wp = Wenc + col * 128 + ks * 32 + quad * 8;
#pragma unroll
      for (int nt = 0; nt < 8; nt++) {
        bf16x8 bf = *(const bf16x8*)(wp + nt * 2048);
        acc[nt] = __builtin_amdgcn_mfma_f32_16x16x32_bf16(af[ks], bf, acc[nt], 0, 0, 0);
      }
    }
    __syncthreads();   // protect tile (chain 1: noop-ish; chain 2: prior reads done)
#pragma unroll
    for (int nt = 0; nt < 8; nt++) {
      float be = benc[nt * 16 + col];
#pragma unroll
      for (int r = 0; r < 4; r++) {
        float v = acc[nt][r] + be;
        v = v > 0.f ? v : 0.01f * v;
        tl[(quad * 4 + r) * 136 + nt * 16 + col] = f2bf(v);
      }
    }
    __syncthreads();
    bf16x8 a2[4];
#pragma unroll
    for (int ks = 0; ks < 4; ks++)
      a2[ks] = *(const bf16x8*)&tl[col * 136 + ks * 32 + quad * 8];

    f32x4 acc2[8];
#pragma unroll
    for (int nt = 0; nt < 8; nt++) acc2[nt] = zero;
#pragma unroll
    for (int ks = 0; ks < 4; ks++) {
      const u16* wp = Wmix + col * 128 + ks * 32 + quad * 8;
#pragma unroll
      for (int nt = 0; nt < 8; nt++) {
        bf16x8 bf = *(const bf16x8*)(wp + nt * 2048);
        acc2[nt] = __builtin_amdgcn_mfma_f32_16x16x32_bf16(a2[ks], bf, acc2[nt], 0, 0, 0);
      }
    }
#pragma unroll
    for (int nt = 0; nt < 8; nt++) {
      float bm = bmix ? bmix[nt * 16 + col] : 0.f;
#pragma unroll
      for (int r = 0; r < 4; r++)
        outp[(size_t)(row0 + quad * 4 + r) * 128 + nt * 16 + col] = f2bf(acc2[nt][r] + bm);
    }
  }
}

// ---------------------------------------------------------------------------
// out = msg@Wrel^T + x@Wroot^T + brel + broot  (fp32 out)
// ---------------------------------------------------------------------------
__global__ __launch_bounds__(256) void out_gemm(
    const float* __restrict__ msg, const u16* __restrict__ xbf,
    const u16* __restrict__ Wrel_b, const u16* __restrict__ Wroot_b,
    const float* __restrict__ brel, const float* __restrict__ broot,
    float* __restrict__ outp)
{
  int wave = blockIdx.x * 4 + (threadIdx.x >> 6);
  int row0 = wave * 16;
  if (row0 >= N_NODES) return;
  int lane = threadIdx.x & 63;
  int col = lane & 15;
  int quad = lane >> 4;

  bf16x8 am[4], ax[4];
#pragma unroll
  for (int ks = 0; ks < 4; ks++) {
    const float* p = msg + (size_t)(row0 + col) * 128 + ks * 32 + quad * 8;
    f32x4 m0 = *(const f32x4*)p;
    f32x4 m1 = *(const f32x4*)(p + 4);
#pragma unroll
    for (int j = 0; j < 4; j++) {
      am[ks][j]     = (short)f2bf(m0[j]);
      am[ks][j + 4] = (short)f2bf(m1[j]);
    }
    ax[ks] = *(const bf16x8*)(xbf + (size_t)(row0 + col) * 128 + ks * 32 + quad * 8);
  }

  f32x4 zero = {0.f, 0.f, 0.f, 0.f};
  f32x4 acc[8];
#pragma unroll
  for (int nt = 0; nt < 8; nt++) acc[nt] = zero;
#pragma unroll
  for (int ks = 0; ks < 4; ks++) {
    const u16* wp1 = Wrel_b + col * 128 + ks * 32 + quad * 8;
    const u16* wp2 = Wroot_b + col * 128 + ks * 32 + quad * 8;
#pragma unroll
    for (int nt = 0; nt < 8; nt++) {
      bf16x8 b1f = *(const bf16x8*)(wp1 + nt * 2048);
      acc[nt] = __builtin_amdgcn_mfma_f32_16x16x32_bf16(am[ks], b1f, acc[nt], 0, 0, 0);
      bf16x8 b2f = *(const bf16x8*)(wp2 + nt * 2048);
      acc[nt] = __builtin_amdgcn_mfma_f32_16x16x32_bf16(ax[ks], b2f, acc[nt], 0, 0, 0);
    }
  }
#pragma unroll
  for (int nt = 0; nt < 8; nt++) {
    int c = nt * 16 + col;
    float b = brel[c] + broot[c];
#pragma unroll
    for (int r = 0; r < 4; r++)
      outp[(size_t)(row0 + quad * 4 + r) * 128 + c] = acc[nt][r] + b;
  }
}

// ---------------------------------------------------------------------------
// Merged edge kernel, both types. Wave = 16 edges.
// Phase 1: bf16 gathers -> |par-cld| A-frags -> 32 MFMAs (t = d@W1c^T)
// LDS transpose t (C-layout -> edge-major, fp32 pitch 132)
// Phase 2: lane = (edge, 32-col strip): vector u/v/W2 loads, relu-dot,
// 4-lane shuffle reduce, sigmoid, vectorized-gather scatter w*x atomics.
// ---------------------------------------------------------------------------
__global__ __launch_bounds__(256) void edge_fused(
    const u16* __restrict__ xa_bf, const u16* __restrict__ xb_bf,
    const int* __restrict__ ei_ab, const int* __restrict__ ei_ba,
    const u16* __restrict__ W1c,
    const u16* __restrict__ u_a, const u16* __restrict__ v_a,
    const u16* __restrict__ u_b, const u16* __restrict__ v_b,
    const float* __restrict__ W2, const float* __restrict__ b2p,
    float* __restrict__ msg_a, float* __restrict__ msg_b)
{
  __shared__ float tld[4][2112];   // 16 rows x pitch 132 fp32, per wave
  int widx = threadIdx.x >> 6;
  int w = blockIdx.x * 4 + widx;   // 0..62499
  int type = (w >= WPT) ? 1 : 0;
  int e0 = (w - type * WPT) * 16;
  const u16* xs = type ? xb_bf : xa_bf;
  const u16* xd = type ? xa_bf : xb_bf;
  const int* ei = type ? ei_ba : ei_ab;
  const u16* uT = type ? u_b : u_a;
  const u16* vT = type ? v_a : v_b;
  float* msg    = type ? msg_a : msg_b;

  int lane = threadIdx.x & 63;
  int col = lane & 15;
  int quad = lane >> 4;

  int em = e0 + col;
  int si = ei[em];
  int di = ei[EDGES + em];

  bf16x8 af[4];
#pragma unroll
  for (int ks = 0; ks < 4; ks++) {
    bf16x8 s8 = *(const bf16x8*)(xs + (size_t)si * 128 + ks * 32 + quad * 8);
    bf16x8 d8 = *(const bf16x8*)(xd + (size_t)di * 128 + ks * 32 + quad * 8);
#pragma unroll
    for (int j = 0; j < 8; j++)
      af[ks][j] = (short)f2bf(__builtin_fabsf(bfe(s8, j) - bfe(d8, j)));
  }

  f32x4 zero = {0.f, 0.f, 0.f, 0.f};
  f32x4 acc[8];
#pragma unroll
  for (int nt = 0; nt < 8; nt++) acc[nt] = zero;
#pragma unroll
  for (int ks = 0; ks < 4; ks++) {
    const u16* wp = W1c + col * 128 + ks * 32 + quad * 8;
#pragma unroll
    for (int nt = 0; nt < 8; nt++) {
      bf16x8 bf = *(const bf16x8*)(wp + nt * 2048);
      acc[nt] = __builtin_amdgcn_mfma_f32_16x16x32_bf16(af[ks], bf, acc[nt], 0, 0, 0);
    }
  }

  float* tl = tld[widx];
#pragma unroll
  for (int nt = 0; nt < 8; nt++)
#pragma unroll
    for (int r = 0; r < 4; r++)
      tl[(quad * 4 + r) * 132 + nt * 16 + col] = acc[nt][r];
  __syncthreads();

  // edge-major epilogue
  int e = e0 + (lane >> 2);
  int s2 = ei[e];
  int d2 = ei[EDGES + e];
  int c0 = (lane & 3) * 32;
  const float* trow = &tl[(lane >> 2) * 132 + c0];
  const u16* urow = uT + (size_t)s2 * 128 + c0;
  const u16* vrow = vT + (size_t)d2 * 128 + c0;

  float p = 0.f;
#pragma unroll
  for (int k = 0; k < 4; k++) {
    f32x4 t0 = *(const f32x4*)(trow + k * 8);
    f32x4 t1 = *(const f32x4*)(trow + k * 8 + 4);
    bf16x8 uu = *(const bf16x8*)(urow + k * 8);
    bf16x8 vv = *(const bf16x8*)(vrow + k * 8);
    f32x4 w0 = *(const f32x4*)(W2 + c0 + k * 8);
    f32x4 w1 = *(const f32x4*)(W2 + c0 + k * 8 + 4);
#pragma unroll
    for (int j = 0; j < 4; j++) {
      float q0 = t0[j] + bfe(uu, j) + bfe(vv, j);
      if (q0 > 0.f) p += q0 * w0[j];
      float q1 = t1[j] + bfe(uu, j + 4) + bfe(vv, j + 4);
      if (q1 > 0.f) p += q1 * w1[j];
    }
  }
  p += __shfl_xor(p, 1, 64);
  p += __shfl_xor(p, 2, 64);
  float wgt = 1.f / (1.f + __expf(-(p + b2p[0])));

  float* mrow = msg + (size_t)d2 * 128 + c0;
  const u16* xrow = xs + (size_t)s2 * 128 + c0;
#pragma unroll
  for (int k = 0; k < 4; k++) {
    bf16x8 xv = *(const bf16x8*)(xrow + k * 8);
#pragma unroll
    for (int j = 0; j < 8; j++)
      unsafeAtomicAdd(mrow + k * 8 + j, wgt * bfe(xv, j));
  }
}

// ---------------------------------------------------------------------------
extern "C" void kernel_launch(void* const* d_in, const int* in_sizes, int n_in,
                              void* d_out, int out_size, void* d_ws, size_t ws_size,
                              hipStream_t stream) {
  const float* x_a      = (const float*)d_in[0];
  const float* x_b      = (const float*)d_in[1];
  const float* Wp       = (const float*)d_in[2];
  const float* bp       = (const float*)d_in[3];
  const float* Wc       = (const float*)d_in[4];
  const float* bc       = (const float*)d_in[5];
  const float* W1       = (const float*)d_in[6];
  const float* b1       = (const float*)d_in[7];
  const float* W2       = (const float*)d_in[8];
  const float* b2       = (const float*)d_in[9];
  const float* Wrel_ab  = (const float*)d_in[10];
  const float* brel_ab  = (const float*)d_in[11];
  const float* Wroot_ab = (const float*)d_in[12];
  const float* broot_ab = (const float*)d_in[13];
  const float* Wrel_ba  = (const float*)d_in[14];
  const float* brel_ba  = (const float*)d_in[15];
  const float* Wroot_ba = (const float*)d_in[16];
  const float* broot_ba = (const float*)d_in[17];
  const int*   ei_ab    = (const int*)d_in[18];
  const int*   ei_ba    = (const int*)d_in[19];

  char* ws = (char*)d_ws;
  u16* Wb        = (u16*)ws;               // 9*16384*2 = 294912 B
  u16* Wp_b      = Wb + 0 * 16384;
  u16* Wc_b      = Wb + 1 * 16384;
  u16* W1a_b     = Wb + 2 * 16384;
  u16* W1b_b     = Wb + 3 * 16384;
  u16* W1c_b     = Wb + 4 * 16384;
  u16* Wrelab_b  = Wb + 5 * 16384;
  u16* Wrootab_b = Wb + 6 * 16384;
  u16* Wrelba_b  = Wb + 7 * 16384;
  u16* Wrootba_b = Wb + 8 * 16384;

  u16* xa_bf = (u16*)(ws + 1048576);       // 12.8 MB each
  u16* xb_bf = (u16*)(ws + 13848576);
  u16* u_a   = (u16*)(ws + 26648576);
  u16* v_a   = (u16*)(ws + 39448576);
  u16* u_b   = (u16*)(ws + 52248576);
  u16* v_b   = (u16*)(ws + 65048576);
  float* msg_a = (float*)(ws + 77848576);  // 25.6 MB each, contiguous pair
  float* msg_b = (float*)(ws + 103448576);

  float* out_a = (float*)d_out;
  float* out_b = out_a + (size_t)N_NODES * 128;

  hipMemsetAsync(msg_a, 0, (size_t)2 * N_NODES * 128 * sizeof(float), stream);

  prep_weights<<<576, 256, 0, stream>>>(Wp, Wc, W1, Wrel_ab, Wroot_ab,
                                        Wrel_ba, Wroot_ba, Wb);
  cast_x<<<6250, 256, 0, stream>>>(x_a, x_b, xa_bf, xb_bf);

  encoder<<<782, 256, 0, stream>>>(xa_bf, Wp_b, bp, Wc_b, bc, W1a_b, b1, W1b_b, u_a, v_a);
  encoder<<<782, 256, 0, stream>>>(xb_bf, Wp_b, bp, Wc_b, bc, W1a_b, b1, W1b_b, u_b, v_b);

  edge_fused<<<15625, 256, 0, stream>>>(xa_bf, xb_bf, ei_ab, ei_ba, W1c_b,
                                        u_a, v_a, u_b, v_b, W2, b2, msg_a, msg_b);

  out_gemm<<<782, 256, 0, stream>>>(msg_a, xa_bf, Wrelba_b, Wrootba_b, brel_ba, broot_ba, out_a);
  out_gemm<<<782, 256, 0, stream>>>(msg_b, xb_bf, Wrelab_b, Wrootab_b, brel_ab, broot_ab, out_b);
}

// Round 3
// 1028.089 us; speedup vs baseline: 6.8289x; 6.8289x over previous
//
#include <hip/hip_runtime.h>
#include <hip/hip_bf16.h>

typedef unsigned short u16;
typedef __attribute__((ext_vector_type(8))) short bf16x8;
typedef __attribute__((ext_vector_type(4))) float f32x4;

#define N_NODES 50000
#define EDGES 500000
#define WPT 31250   // waves per edge type (EDGES/16)

__device__ __forceinline__ u16 f2bf(float f) {
  return __builtin_bit_cast(u16, __float2bfloat16(f));
}
__device__ __forceinline__ float bf2f(u16 u) {
  return __builtin_bit_cast(float, ((unsigned)u) << 16);
}
__device__ __forceinline__ float bfe(bf16x8 v, int j) {
  return bf2f((u16)v[j]);
}

// ---------------------------------------------------------------------------
// weights -> bf16 tables (9 x 128x128 row-major)
// 0 Wp, 1 Wc, 2 W1a, 3 W1b, 4 W1c, 5 Wrel_ab, 6 Wroot_ab, 7 Wrel_ba, 8 Wroot_ba
// ---------------------------------------------------------------------------
__global__ __launch_bounds__(256) void prep_weights(
    const float* __restrict__ Wp, const float* __restrict__ Wc,
    const float* __restrict__ W1,
    const float* __restrict__ Wrel_ab, const float* __restrict__ Wroot_ab,
    const float* __restrict__ Wrel_ba, const float* __restrict__ Wroot_ba,
    u16* __restrict__ out)
{
  int tid = blockIdx.x * 256 + threadIdx.x;  // 9*16384
  int m = tid >> 14;
  int idx = tid & 16383;
  int r = idx >> 7;
  int c = idx & 127;
  float val;
  switch (m) {
    case 0: val = Wp[r * 128 + c]; break;
    case 1: val = Wc[r * 128 + c]; break;
    case 2: val = W1[r * 384 + c]; break;
    case 3: val = W1[r * 384 + 128 + c]; break;
    case 4: val = W1[r * 384 + 256 + c]; break;
    case 5: val = Wrel_ab[r * 128 + c]; break;
    case 6: val = Wroot_ab[r * 128 + c]; break;
    case 7: val = Wrel_ba[r * 128 + c]; break;
    default: val = Wroot_ba[r * 128 + c]; break;
  }
  out[tid] = f2bf(val);
}

// ---------------------------------------------------------------------------
// x (fp32) -> bf16 tables, 8 elems/thread
// ---------------------------------------------------------------------------
__global__ __launch_bounds__(256) void cast_x(
    const float* __restrict__ xa, const float* __restrict__ xb,
    u16* __restrict__ oa, u16* __restrict__ ob)
{
  int t = blockIdx.x * 256 + threadIdx.x;    // 1,600,000 threads
  const int HALF = (N_NODES * 128) / 8;      // 800,000
  const float* src;
  u16* dst;
  int idx;
  if (t < HALF) { src = xa; dst = oa; idx = t * 8; }
  else          { src = xb; dst = ob; idx = (t - HALF) * 8; }
  f32x4 a = *(const f32x4*)(src + idx);
  f32x4 b = *(const f32x4*)(src + idx + 4);
  bf16x8 o;
#pragma unroll
  for (int j = 0; j < 4; j++) {
    o[j]     = (short)f2bf(a[j]);
    o[j + 4] = (short)f2bf(b[j]);
  }
  *(bf16x8*)(dst + idx) = o;
}

// ---------------------------------------------------------------------------
// Fused encoder: per node set computes
//   u = lrelu(x@Wp^T+bp) @ W1a^T + b1   (b1 folded in!)
//   v = lrelu(x@Wc^T+bc) @ W1b^T
// One wave = 16 rows; intermediate transposed C-layout -> A-layout via LDS.
// ---------------------------------------------------------------------------
__global__ __launch_bounds__(256) void encoder(
    const u16* __restrict__ xbf,
    const u16* __restrict__ Wp_b, const float* __restrict__ bp,
    const u16* __restrict__ Wc_b, const float* __restrict__ bc,
    const u16* __restrict__ W1a_b, const float* __restrict__ b1,
    const u16* __restrict__ W1b_b,
    u16* __restrict__ u_out, u16* __restrict__ v_out)
{
  __shared__ u16 tile[4][2176];   // 16 rows x pitch 136 bf16, per wave
  int widx = threadIdx.x >> 6;
  int wave = blockIdx.x * 4 + widx;
  if (wave > (N_NODES / 16 - 1)) wave = N_NODES / 16 - 1;  // clamp: dup work, all reach barriers
  int row0 = wave * 16;
  int lane = threadIdx.x & 63;
  int col = lane & 15;
  int quad = lane >> 4;
  u16* tl = tile[widx];

  bf16x8 af[4];
#pragma unroll
  for (int ks = 0; ks < 4; ks++)
    af[ks] = *(const bf16x8*)(xbf + (size_t)(row0 + col) * 128 + ks * 32 + quad * 8);

  f32x4 zero = {0.f, 0.f, 0.f, 0.f};

  for (int chain = 0; chain < 2; chain++) {
    const u16* Wenc = chain ? Wc_b : Wp_b;
    const float* benc = chain ? bc : bp;
    const u16* Wmix = chain ? W1b_b : W1a_b;
    const float* bmix = chain ? nullptr : b1;
    u16* outp = chain ? v_out : u_out;

    f32x4 acc[8];
#pragma unroll
    for (int nt = 0; nt < 8; nt++) acc[nt] = zero;
#pragma unroll
    for (int ks = 0; ks < 4; ks++) {
      const u16* wp = Wenc + col * 128 + ks * 32 + quad * 8;
#pragma unroll
      for (int nt = 0; nt < 8; nt++) {
        bf16x8 bf = *(const bf16x8*)(wp + nt * 2048);
        acc[nt] = __builtin_amdgcn_mfma_f32_16x16x32_bf16(af[ks], bf, acc[nt], 0, 0, 0);
      }
    }
    __syncthreads();   // protect tile (chain 2: prior reads done)
#pragma unroll
    for (int nt = 0; nt < 8; nt++) {
      float be = benc[nt * 16 + col];
#pragma unroll
      for (int r = 0; r < 4; r++) {
        float v = acc[nt][r] + be;
        v = v > 0.f ? v : 0.01f * v;
        tl[(quad * 4 + r) * 136 + nt * 16 + col] = f2bf(v);
      }
    }
    __syncthreads();
    bf16x8 a2[4];
#pragma unroll
    for (int ks = 0; ks < 4; ks++)
      a2[ks] = *(const bf16x8*)&tl[col * 136 + ks * 32 + quad * 8];

    f32x4 acc2[8];
#pragma unroll
    for (int nt = 0; nt < 8; nt++) acc2[nt] = zero;
#pragma unroll
    for (int ks = 0; ks < 4; ks++) {
      const u16* wp = Wmix + col * 128 + ks * 32 + quad * 8;
#pragma unroll
      for (int nt = 0; nt < 8; nt++) {
        bf16x8 bf = *(const bf16x8*)(wp + nt * 2048);
        acc2[nt] = __builtin_amdgcn_mfma_f32_16x16x32_bf16(a2[ks], bf, acc2[nt], 0, 0, 0);
      }
    }
#pragma unroll
    for (int nt = 0; nt < 8; nt++) {
      float bm = bmix ? bmix[nt * 16 + col] : 0.f;
#pragma unroll
      for (int r = 0; r < 4; r++)
        outp[(size_t)(row0 + quad * 4 + r) * 128 + nt * 16 + col] = f2bf(acc2[nt][r] + bm);
    }
  }
}

// ---------------------------------------------------------------------------
// out = msg@Wrel^T + x@Wroot^T + brel + broot  (fp32 out)
// ---------------------------------------------------------------------------
__global__ __launch_bounds__(256) void out_gemm(
    const float* __restrict__ msg, const u16* __restrict__ xbf,
    const u16* __restrict__ Wrel_b, const u16* __restrict__ Wroot_b,
    const float* __restrict__ brel, const float* __restrict__ broot,
    float* __restrict__ outp)
{
  int wave = blockIdx.x * 4 + (threadIdx.x >> 6);
  int row0 = wave * 16;
  if (row0 >= N_NODES) return;
  int lane = threadIdx.x & 63;
  int col = lane & 15;
  int quad = lane >> 4;

  bf16x8 am[4], ax[4];
#pragma unroll
  for (int ks = 0; ks < 4; ks++) {
    const float* p = msg + (size_t)(row0 + col) * 128 + ks * 32 + quad * 8;
    f32x4 m0 = *(const f32x4*)p;
    f32x4 m1 = *(const f32x4*)(p + 4);
#pragma unroll
    for (int j = 0; j < 4; j++) {
      am[ks][j]     = (short)f2bf(m0[j]);
      am[ks][j + 4] = (short)f2bf(m1[j]);
    }
    ax[ks] = *(const bf16x8*)(xbf + (size_t)(row0 + col) * 128 + ks * 32 + quad * 8);
  }

  f32x4 zero = {0.f, 0.f, 0.f, 0.f};
  f32x4 acc[8];
#pragma unroll
  for (int nt = 0; nt < 8; nt++) acc[nt] = zero;
#pragma unroll
  for (int ks = 0; ks < 4; ks++) {
    const u16* wp1 = Wrel_b + col * 128 + ks * 32 + quad * 8;
    const u16* wp2 = Wroot_b + col * 128 + ks * 32 + quad * 8;
#pragma unroll
    for (int nt = 0; nt < 8; nt++) {
      bf16x8 b1f = *(const bf16x8*)(wp1 + nt * 2048);
      acc[nt] = __builtin_amdgcn_mfma_f32_16x16x32_bf16(am[ks], b1f, acc[nt], 0, 0, 0);
      bf16x8 b2f = *(const bf16x8*)(wp2 + nt * 2048);
      acc[nt] = __builtin_amdgcn_mfma_f32_16x16x32_bf16(ax[ks], b2f, acc[nt], 0, 0, 0);
    }
  }
#pragma unroll
  for (int nt = 0; nt < 8; nt++) {
    int c = nt * 16 + col;
    float b = brel[c] + broot[c];
#pragma unroll
    for (int r = 0; r < 4; r++)
      outp[(size_t)(row0 + quad * 4 + r) * 128 + c] = acc[nt][r] + b;
  }
}

// ---------------------------------------------------------------------------
// Merged edge kernel, both types. Wave = 16 edges.
// Phase 1: bf16 gathers -> |par-cld| A-frags -> 32 MFMAs (t = d@W1c^T)
// LDS transpose t (C-layout -> edge-major, fp32 pitch 132)
// Phase 2: lane = (edge, 32-col strip): vector u/v/W2 loads, relu-dot,
// 4-lane shuffle reduce, sigmoid.
// Scatter: R1-coalesced pattern — per r, quad q handles edge q*4+r, the 16
// col-lanes write 16 CONSECUTIVE floats (4 cache lines per atomic instr,
// 16 lanes/line). wgt/src/dst distributed via cross-lane shuffles.
// ---------------------------------------------------------------------------
__global__ __launch_bounds__(256) void edge_fused(
    const u16* __restrict__ xa_bf, const u16* __restrict__ xb_bf,
    const int* __restrict__ ei_ab, const int* __restrict__ ei_ba,
    const u16* __restrict__ W1c,
    const u16* __restrict__ u_a, const u16* __restrict__ v_a,
    const u16* __restrict__ u_b, const u16* __restrict__ v_b,
    const float* __restrict__ W2, const float* __restrict__ b2p,
    float* __restrict__ msg_a, float* __restrict__ msg_b)
{
  __shared__ float tld[4][2112];   // 16 rows x pitch 132 fp32, per wave
  int widx = threadIdx.x >> 6;
  int w = blockIdx.x * 4 + widx;   // 0..62499
  int type = (w >= WPT) ? 1 : 0;
  int e0 = (w - type * WPT) * 16;
  const u16* xs = type ? xb_bf : xa_bf;
  const u16* xd = type ? xa_bf : xb_bf;
  const int* ei = type ? ei_ba : ei_ab;
  const u16* uT = type ? u_b : u_a;
  const u16* vT = type ? v_a : v_b;
  float* msg    = type ? msg_a : msg_b;

  int lane = threadIdx.x & 63;
  int col = lane & 15;
  int quad = lane >> 4;

  int em = e0 + col;
  int si = ei[em];
  int di = ei[EDGES + em];

  bf16x8 af[4];
#pragma unroll
  for (int ks = 0; ks < 4; ks++) {
    bf16x8 s8 = *(const bf16x8*)(xs + (size_t)si * 128 + ks * 32 + quad * 8);
    bf16x8 d8 = *(const bf16x8*)(xd + (size_t)di * 128 + ks * 32 + quad * 8);
#pragma unroll
    for (int j = 0; j < 8; j++)
      af[ks][j] = (short)f2bf(__builtin_fabsf(bfe(s8, j) - bfe(d8, j)));
  }

  f32x4 zero = {0.f, 0.f, 0.f, 0.f};
  f32x4 acc[8];
#pragma unroll
  for (int nt = 0; nt < 8; nt++) acc[nt] = zero;
#pragma unroll
  for (int ks = 0; ks < 4; ks++) {
    const u16* wp = W1c + col * 128 + ks * 32 + quad * 8;
#pragma unroll
    for (int nt = 0; nt < 8; nt++) {
      bf16x8 bf = *(const bf16x8*)(wp + nt * 2048);
      acc[nt] = __builtin_amdgcn_mfma_f32_16x16x32_bf16(af[ks], bf, acc[nt], 0, 0, 0);
    }
  }

  float* tl = tld[widx];
#pragma unroll
  for (int nt = 0; nt < 8; nt++)
#pragma unroll
    for (int r = 0; r < 4; r++)
      tl[(quad * 4 + r) * 132 + nt * 16 + col] = acc[nt][r];
  __syncthreads();

  // edge-major epilogue: lane = (edge = lane>>2, strip = (lane&3)*32)
  int e = e0 + (lane >> 2);
  int s2 = ei[e];
  int d2 = ei[EDGES + e];
  int c0 = (lane & 3) * 32;
  const float* trow = &tl[(lane >> 2) * 132 + c0];
  const u16* urow = uT + (size_t)s2 * 128 + c0;
  const u16* vrow = vT + (size_t)d2 * 128 + c0;

  float p = 0.f;
#pragma unroll
  for (int k = 0; k < 4; k++) {
    f32x4 t0 = *(const f32x4*)(trow + k * 8);
    f32x4 t1 = *(const f32x4*)(trow + k * 8 + 4);
    bf16x8 uu = *(const bf16x8*)(urow + k * 8);
    bf16x8 vv = *(const bf16x8*)(vrow + k * 8);
    f32x4 w0 = *(const f32x4*)(W2 + c0 + k * 8);
    f32x4 w1 = *(const f32x4*)(W2 + c0 + k * 8 + 4);
#pragma unroll
    for (int j = 0; j < 4; j++) {
      float q0 = t0[j] + bfe(uu, j) + bfe(vv, j);
      if (q0 > 0.f) p += q0 * w0[j];
      float q1 = t1[j] + bfe(uu, j + 4) + bfe(vv, j + 4);
      if (q1 > 0.f) p += q1 * w1[j];
    }
  }
  p += __shfl_xor(p, 1, 64);
  p += __shfl_xor(p, 2, 64);
  float wgt = 1.f / (1.f + __expf(-(p + b2p[0])));

  // coalesced scatter (R1 pattern), wgt/s/d moved via shuffles
#pragma unroll
  for (int r = 0; r < 4; r++) {
    int src_lane = (quad * 4 + r) * 4;   // lane group holding edge quad*4+r
    float wr = __shfl(wgt, src_lane, 64);
    int sr = __shfl(s2, src_lane, 64);
    int dr = __shfl(d2, src_lane, 64);
    const u16* xrow = xs + (size_t)sr * 128;
    float* mrow = msg + (size_t)dr * 128;
#pragma unroll
    for (int nt = 0; nt < 8; nt++) {
      int c = nt * 16 + col;
      unsafeAtomicAdd(mrow + c, wr * bf2f(xrow[c]));
    }
  }
}

// ---------------------------------------------------------------------------
extern "C" void kernel_launch(void* const* d_in, const int* in_sizes, int n_in,
                              void* d_out, int out_size, void* d_ws, size_t ws_size,
                              hipStream_t stream) {
  const float* x_a      = (const float*)d_in[0];
  const float* x_b      = (const float*)d_in[1];
  const float* Wp       = (const float*)d_in[2];
  const float* bp       = (const float*)d_in[3];
  const float* Wc       = (const float*)d_in[4];
  const float* bc       = (const float*)d_in[5];
  const float* W1       = (const float*)d_in[6];
  const float* b1       = (const float*)d_in[7];
  const float* W2       = (const float*)d_in[8];
  const float* b2       = (const float*)d_in[9];
  const float* Wrel_ab  = (const float*)d_in[10];
  const float* brel_ab  = (const float*)d_in[11];
  const float* Wroot_ab = (const float*)d_in[12];
  const float* broot_ab = (const float*)d_in[13];
  const float* Wrel_ba  = (const float*)d_in[14];
  const float* brel_ba  = (const float*)d_in[15];
  const float* Wroot_ba = (const float*)d_in[16];
  const float* broot_ba = (const float*)d_in[17];
  const int*   ei_ab    = (const int*)d_in[18];
  const int*   ei_ba    = (const int*)d_in[19];

  char* ws = (char*)d_ws;
  u16* Wb        = (u16*)ws;               // 9*16384*2 = 294912 B
  u16* Wp_b      = Wb + 0 * 16384;
  u16* Wc_b      = Wb + 1 * 16384;
  u16* W1a_b     = Wb + 2 * 16384;
  u16* W1b_b     = Wb + 3 * 16384;
  u16* W1c_b     = Wb + 4 * 16384;
  u16* Wrelab_b  = Wb + 5 * 16384;
  u16* Wrootab_b = Wb + 6 * 16384;
  u16* Wrelba_b  = Wb + 7 * 16384;
  u16* Wrootba_b = Wb + 8 * 16384;

  u16* xa_bf = (u16*)(ws + 1048576);       // 12.8 MB each
  u16* xb_bf = (u16*)(ws + 13848576);
  u16* u_a   = (u16*)(ws + 26648576);
  u16* v_a   = (u16*)(ws + 39448576);
  u16* u_b   = (u16*)(ws + 52248576);
  u16* v_b   = (u16*)(ws + 65048576);
  float* msg_a = (float*)(ws + 77848576);  // 25.6 MB each, contiguous pair
  float* msg_b = (float*)(ws + 103448576);

  float* out_a = (float*)d_out;
  float* out_b = out_a + (size_t)N_NODES * 128;

  hipMemsetAsync(msg_a, 0, (size_t)2 * N_NODES * 128 * sizeof(float), stream);

  prep_weights<<<576, 256, 0, stream>>>(Wp, Wc, W1, Wrel_ab, Wroot_ab,
                                        Wrel_ba, Wroot_ba, Wb);
  cast_x<<<6250, 256, 0, stream>>>(x_a, x_b, xa_bf, xb_bf);

  encoder<<<782, 256, 0, stream>>>(xa_bf, Wp_b, bp, Wc_b, bc, W1a_b, b1, W1b_b, u_a, v_a);
  encoder<<<782, 256, 0, stream>>>(xb_bf, Wp_b, bp, Wc_b, bc, W1a_b, b1, W1b_b, u_b, v_b);

  edge_fused<<<15625, 256, 0, stream>>>(xa_bf, xb_bf, ei_ab, ei_ba, W1c_b,
                                        u_a, v_a, u_b, v_b, W2, b2, msg_a, msg_b);

  out_gemm<<<782, 256, 0, stream>>>(msg_a, xa_bf, Wrelba_b, Wrootba_b, brel_ba, broot_ba, out_a);
  out_gemm<<<782, 256, 0, stream>>>(msg_b, xb_bf, Wrelab_b, Wrootab_b, brel_ab, broot_ab, out_b);
}

// Round 4
// 772.248 us; speedup vs baseline: 9.0913x; 1.3313x over previous
//
#include <hip/hip_runtime.h>
#include <hip/hip_bf16.h>

typedef unsigned short u16;
typedef __attribute__((ext_vector_type(8))) short bf16x8;
typedef __attribute__((ext_vector_type(2))) short s16x2;
typedef __attribute__((ext_vector_type(4))) float f32x4;

#define N_NODES 50000
#define EDGES 500000
#define WPT 31250     // edge waves per type
#define NWAVES 3125   // node waves per type (50000/16)
#define NBLK 782      // ceil(NWAVES/4)

__device__ __forceinline__ u16 f2bf(float f) {
  return __builtin_bit_cast(u16, __float2bfloat16(f));
}
__device__ __forceinline__ float bf2f(u16 u) {
  return __builtin_bit_cast(float, ((unsigned)u) << 16);
}
__device__ __forceinline__ float bfe(bf16x8 v, int j) {
  return bf2f((u16)v[j]);
}

// packed bf16 atomic add (2 values at 4B-aligned address)
__device__ __forceinline__ void pk_atomic_bf16(u16* addr, float lo, float hi) {
#if __has_builtin(__builtin_amdgcn_global_atomic_fadd_v2bf16)
  s16x2 v;
  v[0] = (short)f2bf(lo);
  v[1] = (short)f2bf(hi);
  __builtin_amdgcn_global_atomic_fadd_v2bf16(
      (__attribute__((address_space(1))) s16x2*)addr, v);
#else
  unsigned* p = (unsigned*)addr;
  unsigned old = *p, assumed;
  do {
    assumed = old;
    float l2 = bf2f((u16)(assumed & 0xffff)) + lo;
    float h2 = bf2f((u16)(assumed >> 16)) + hi;
    unsigned nv = (unsigned)f2bf(l2) | ((unsigned)f2bf(h2) << 16);
    old = atomicCAS(p, assumed, nv);
  } while (old != assumed);
#endif
}

// ---------------------------------------------------------------------------
// weights -> bf16 tables (9 x 128x128 row-major)
// 0 Wp, 1 Wc, 2 W1a, 3 W1b, 4 W1c, 5 Wrel_ab, 6 Wroot_ab, 7 Wrel_ba, 8 Wroot_ba
// ---------------------------------------------------------------------------
__global__ __launch_bounds__(256) void prep_weights(
    const float* __restrict__ Wp, const float* __restrict__ Wc,
    const float* __restrict__ W1,
    const float* __restrict__ Wrel_ab, const float* __restrict__ Wroot_ab,
    const float* __restrict__ Wrel_ba, const float* __restrict__ Wroot_ba,
    u16* __restrict__ out)
{
  int tid = blockIdx.x * 256 + threadIdx.x;  // 9*16384
  int m = tid >> 14;
  int idx = tid & 16383;
  int r = idx >> 7;
  int c = idx & 127;
  float val;
  switch (m) {
    case 0: val = Wp[r * 128 + c]; break;
    case 1: val = Wc[r * 128 + c]; break;
    case 2: val = W1[r * 384 + c]; break;
    case 3: val = W1[r * 384 + 128 + c]; break;
    case 4: val = W1[r * 384 + 256 + c]; break;
    case 5: val = Wrel_ab[r * 128 + c]; break;
    case 6: val = Wroot_ab[r * 128 + c]; break;
    case 7: val = Wrel_ba[r * 128 + c]; break;
    default: val = Wroot_ba[r * 128 + c]; break;
  }
  out[tid] = f2bf(val);
}

// ---------------------------------------------------------------------------
// x (fp32) -> bf16 tables, 8 elems/thread
// ---------------------------------------------------------------------------
__global__ __launch_bounds__(256) void cast_x(
    const float* __restrict__ xa, const float* __restrict__ xb,
    u16* __restrict__ oa, u16* __restrict__ ob)
{
  int t = blockIdx.x * 256 + threadIdx.x;    // 1,600,000 threads
  const int HALF = (N_NODES * 128) / 8;      // 800,000
  const float* src;
  u16* dst;
  int idx;
  if (t < HALF) { src = xa; dst = oa; idx = t * 8; }
  else          { src = xb; dst = ob; idx = (t - HALF) * 8; }
  f32x4 a = *(const f32x4*)(src + idx);
  f32x4 b = *(const f32x4*)(src + idx + 4);
  bf16x8 o;
#pragma unroll
  for (int j = 0; j < 4; j++) {
    o[j]     = (short)f2bf(a[j]);
    o[j + 4] = (short)f2bf(b[j]);
  }
  *(bf16x8*)(dst + idx) = o;
}

// ---------------------------------------------------------------------------
// Fused encoder, both node sets in one dispatch (grid 2*NBLK):
//   u = lrelu(x@Wp^T+bp) @ W1a^T + b1   (b1 folded in)
//   v = lrelu(x@Wc^T+bc) @ W1b^T
// ---------------------------------------------------------------------------
__global__ __launch_bounds__(256) void encoder2(
    const u16* __restrict__ xa_bf, const u16* __restrict__ xb_bf,
    const u16* __restrict__ Wp_b, const float* __restrict__ bp,
    const u16* __restrict__ Wc_b, const float* __restrict__ bc,
    const u16* __restrict__ W1a_b, const float* __restrict__ b1,
    const u16* __restrict__ W1b_b,
    u16* __restrict__ u_a, u16* __restrict__ v_a,
    u16* __restrict__ u_b, u16* __restrict__ v_b)
{
  __shared__ u16 tile[4][2176];   // 16 x pitch 136 bf16, per wave
  int widx = threadIdx.x >> 6;
  int w = blockIdx.x * 4 + widx;         // 0 .. 2*4*NBLK-1
  int type = (w >= NBLK * 4) ? 1 : 0;
  int nw = w - type * NBLK * 4;
  if (nw >= NWAVES) nw = NWAVES - 1;     // clamp (dup work; barriers stay uniform)
  const u16* xbf = type ? xb_bf : xa_bf;
  u16* u_out = type ? u_b : u_a;
  u16* v_out = type ? v_b : v_a;
  int row0 = nw * 16;
  int lane = threadIdx.x & 63;
  int col = lane & 15;
  int quad = lane >> 4;
  u16* tl = tile[widx];

  bf16x8 af[4];
#pragma unroll
  for (int ks = 0; ks < 4; ks++)
    af[ks] = *(const bf16x8*)(xbf + (size_t)(row0 + col) * 128 + ks * 32 + quad * 8);

  f32x4 zero = {0.f, 0.f, 0.f, 0.f};

  for (int chain = 0; chain < 2; chain++) {
    const u16* Wenc = chain ? Wc_b : Wp_b;
    const float* benc = chain ? bc : bp;
    const u16* Wmix = chain ? W1b_b : W1a_b;
    const float* bmix = chain ? nullptr : b1;
    u16* outp = chain ? v_out : u_out;

    f32x4 acc[8];
#pragma unroll
    for (int nt = 0; nt < 8; nt++) acc[nt] = zero;
#pragma unroll
    for (int ks = 0; ks < 4; ks++) {
      const u16* wp = Wenc + col * 128 + ks * 32 + quad * 8;
#pragma unroll
      for (int nt = 0; nt < 8; nt++) {
        bf16x8 bf = *(const bf16x8*)(wp + nt * 2048);
        acc[nt] = __builtin_amdgcn_mfma_f32_16x16x32_bf16(af[ks], bf, acc[nt], 0, 0, 0);
      }
    }
    __syncthreads();
#pragma unroll
    for (int nt = 0; nt < 8; nt++) {
      float be = benc[nt * 16 + col];
#pragma unroll
      for (int r = 0; r < 4; r++) {
        float v = acc[nt][r] + be;
        v = v > 0.f ? v : 0.01f * v;
        tl[(quad * 4 + r) * 136 + nt * 16 + col] = f2bf(v);
      }
    }
    __syncthreads();
    bf16x8 a2[4];
#pragma unroll
    for (int ks = 0; ks < 4; ks++)
      a2[ks] = *(const bf16x8*)&tl[col * 136 + ks * 32 + quad * 8];

    f32x4 acc2[8];
#pragma unroll
    for (int nt = 0; nt < 8; nt++) acc2[nt] = zero;
#pragma unroll
    for (int ks = 0; ks < 4; ks++) {
      const u16* wp = Wmix + col * 128 + ks * 32 + quad * 8;
#pragma unroll
      for (int nt = 0; nt < 8; nt++) {
        bf16x8 bf = *(const bf16x8*)(wp + nt * 2048);
        acc2[nt] = __builtin_amdgcn_mfma_f32_16x16x32_bf16(a2[ks], bf, acc2[nt], 0, 0, 0);
      }
    }
#pragma unroll
    for (int nt = 0; nt < 8; nt++) {
      float bm = bmix ? bmix[nt * 16 + col] : 0.f;
#pragma unroll
      for (int r = 0; r < 4; r++)
        outp[(size_t)(row0 + quad * 4 + r) * 128 + nt * 16 + col] = f2bf(acc2[nt][r] + bm);
    }
  }
}

// ---------------------------------------------------------------------------
// y = x @ Wrel^T (bf16 out), both types in one dispatch.
// type 0: y_ab = x_a @ Wrel_ab^T ; type 1: y_ba = x_b @ Wrel_ba^T
// ---------------------------------------------------------------------------
__global__ __launch_bounds__(256) void y_gemm2(
    const u16* __restrict__ xa_bf, const u16* __restrict__ xb_bf,
    const u16* __restrict__ Wrelab_b, const u16* __restrict__ Wrelba_b,
    u16* __restrict__ y_ab, u16* __restrict__ y_ba)
{
  int w = blockIdx.x * 4 + (threadIdx.x >> 6);
  int type = (w >= NBLK * 4) ? 1 : 0;
  int nw = w - type * NBLK * 4;
  if (nw >= NWAVES) return;
  const u16* xbf = type ? xb_bf : xa_bf;
  const u16* Wb = type ? Wrelba_b : Wrelab_b;
  u16* yout = type ? y_ba : y_ab;
  int row0 = nw * 16;
  int lane = threadIdx.x & 63;
  int col = lane & 15;
  int quad = lane >> 4;

  bf16x8 af[4];
#pragma unroll
  for (int ks = 0; ks < 4; ks++)
    af[ks] = *(const bf16x8*)(xbf + (size_t)(row0 + col) * 128 + ks * 32 + quad * 8);

  f32x4 zero = {0.f, 0.f, 0.f, 0.f};
  f32x4 acc[8];
#pragma unroll
  for (int nt = 0; nt < 8; nt++) acc[nt] = zero;
#pragma unroll
  for (int ks = 0; ks < 4; ks++) {
    const u16* wp = Wb + col * 128 + ks * 32 + quad * 8;
#pragma unroll
    for (int nt = 0; nt < 8; nt++) {
      bf16x8 bf = *(const bf16x8*)(wp + nt * 2048);
      acc[nt] = __builtin_amdgcn_mfma_f32_16x16x32_bf16(af[ks], bf, acc[nt], 0, 0, 0);
    }
  }
#pragma unroll
  for (int nt = 0; nt < 8; nt++)
#pragma unroll
    for (int r = 0; r < 4; r++)
      yout[(size_t)(row0 + quad * 4 + r) * 128 + nt * 16 + col] = f2bf(acc[nt][r]);
}

// ---------------------------------------------------------------------------
// out = x@Wroot^T + msgY + brel + broot  (fp32 out), both types.
// ---------------------------------------------------------------------------
__global__ __launch_bounds__(256) void out_gemm2(
    const u16* __restrict__ xa_bf, const u16* __restrict__ xb_bf,
    const u16* __restrict__ msgY_a, const u16* __restrict__ msgY_b,
    const u16* __restrict__ Wrootba_b, const u16* __restrict__ Wrootab_b,
    const float* __restrict__ brel_ba, const float* __restrict__ broot_ba,
    const float* __restrict__ brel_ab, const float* __restrict__ broot_ab,
    float* __restrict__ out_a, float* __restrict__ out_b)
{
  int w = blockIdx.x * 4 + (threadIdx.x >> 6);
  int type = (w >= NBLK * 4) ? 1 : 0;
  int nw = w - type * NBLK * 4;
  if (nw >= NWAVES) return;
  const u16* xbf = type ? xb_bf : xa_bf;
  const u16* msgY = type ? msgY_b : msgY_a;
  const u16* Wb = type ? Wrootab_b : Wrootba_b;
  const float* brel = type ? brel_ab : brel_ba;
  const float* broot = type ? broot_ab : broot_ba;
  float* outp = type ? out_b : out_a;
  int row0 = nw * 16;
  int lane = threadIdx.x & 63;
  int col = lane & 15;
  int quad = lane >> 4;

  bf16x8 af[4];
#pragma unroll
  for (int ks = 0; ks < 4; ks++)
    af[ks] = *(const bf16x8*)(xbf + (size_t)(row0 + col) * 128 + ks * 32 + quad * 8);

  f32x4 zero = {0.f, 0.f, 0.f, 0.f};
  f32x4 acc[8];
#pragma unroll
  for (int nt = 0; nt < 8; nt++) acc[nt] = zero;
#pragma unroll
  for (int ks = 0; ks < 4; ks++) {
    const u16* wp = Wb + col * 128 + ks * 32 + quad * 8;
#pragma unroll
    for (int nt = 0; nt < 8; nt++) {
      bf16x8 bf = *(const bf16x8*)(wp + nt * 2048);
      acc[nt] = __builtin_amdgcn_mfma_f32_16x16x32_bf16(af[ks], bf, acc[nt], 0, 0, 0);
    }
  }
#pragma unroll
  for (int nt = 0; nt < 8; nt++) {
    int c = nt * 16 + col;
    float b = brel[c] + broot[c];
#pragma unroll
    for (int r = 0; r < 4; r++) {
      size_t row = row0 + quad * 4 + r;
      outp[row * 128 + c] = acc[nt][r] + b + bf2f(msgY[row * 128 + c]);
    }
  }
}

// ---------------------------------------------------------------------------
// Merged edge kernel, both types. Wave = 16 edges.
// Phase 1: bf16 gathers -> |par-cld| A-frags -> 32 MFMAs (t = d@W1c^T)
// LDS transpose (bf16, pitch 136)
// Phase 2: lane=(edge, 32-col strip): vector t/u/v/W2 loads, relu-dot,
// shuffle reduce, sigmoid.
// Scatter: coalesced pk_add_bf16 of w * y_src into msgY (16 insts/wave).
// ---------------------------------------------------------------------------
__global__ __launch_bounds__(256) void edge_fused(
    const u16* __restrict__ xa_bf, const u16* __restrict__ xb_bf,
    const int* __restrict__ ei_ab, const int* __restrict__ ei_ba,
    const u16* __restrict__ W1c,
    const u16* __restrict__ u_a, const u16* __restrict__ v_a,
    const u16* __restrict__ u_b, const u16* __restrict__ v_b,
    const u16* __restrict__ y_ab, const u16* __restrict__ y_ba,
    const float* __restrict__ W2, const float* __restrict__ b2p,
    u16* __restrict__ msgY_a, u16* __restrict__ msgY_b)
{
  __shared__ u16 tld[4][2176];   // 16 x pitch 136 bf16, per wave (17.4 KB)
  int widx = threadIdx.x >> 6;
  int w = blockIdx.x * 4 + widx;   // 0..62499
  int type = (w >= WPT) ? 1 : 0;
  int e0 = (w - type * WPT) * 16;
  const u16* xs = type ? xb_bf : xa_bf;
  const u16* xd = type ? xa_bf : xb_bf;
  const int* ei = type ? ei_ba : ei_ab;
  const u16* uT = type ? u_b : u_a;
  const u16* vT = type ? v_a : v_b;
  const u16* yT = type ? y_ba : y_ab;
  u16* msgY     = type ? msgY_a : msgY_b;

  int lane = threadIdx.x & 63;
  int col = lane & 15;
  int quad = lane >> 4;

  int em = e0 + col;
  int si = ei[em];
  int di = ei[EDGES + em];

  bf16x8 af[4];
#pragma unroll
  for (int ks = 0; ks < 4; ks++) {
    bf16x8 s8 = *(const bf16x8*)(xs + (size_t)si * 128 + ks * 32 + quad * 8);
    bf16x8 d8 = *(const bf16x8*)(xd + (size_t)di * 128 + ks * 32 + quad * 8);
#pragma unroll
    for (int j = 0; j < 8; j++)
      af[ks][j] = (short)f2bf(__builtin_fabsf(bfe(s8, j) - bfe(d8, j)));
  }

  f32x4 zero = {0.f, 0.f, 0.f, 0.f};
  f32x4 acc[8];
#pragma unroll
  for (int nt = 0; nt < 8; nt++) acc[nt] = zero;
#pragma unroll
  for (int ks = 0; ks < 4; ks++) {
    const u16* wp = W1c + col * 128 + ks * 32 + quad * 8;
#pragma unroll
    for (int nt = 0; nt < 8; nt++) {
      bf16x8 bf = *(const bf16x8*)(wp + nt * 2048);
      acc[nt] = __builtin_amdgcn_mfma_f32_16x16x32_bf16(af[ks], bf, acc[nt], 0, 0, 0);
    }
  }

  u16* tl = tld[widx];
#pragma unroll
  for (int nt = 0; nt < 8; nt++)
#pragma unroll
    for (int r = 0; r < 4; r++)
      tl[(quad * 4 + r) * 136 + nt * 16 + col] = f2bf(acc[nt][r]);
  __syncthreads();

  // edge-major epilogue: lane = (edge = lane>>2, strip = (lane&3)*32)
  int e = e0 + (lane >> 2);
  int s2 = ei[e];
  int d2 = ei[EDGES + e];
  int c0 = (lane & 3) * 32;
  const u16* trow = &tl[(lane >> 2) * 136 + c0];
  const u16* urow = uT + (size_t)s2 * 128 + c0;
  const u16* vrow = vT + (size_t)d2 * 128 + c0;

  float p = 0.f;
#pragma unroll
  for (int k = 0; k < 4; k++) {
    bf16x8 tt = *(const bf16x8*)(trow + k * 8);
    bf16x8 uu = *(const bf16x8*)(urow + k * 8);
    bf16x8 vv = *(const bf16x8*)(vrow + k * 8);
    f32x4 w0 = *(const f32x4*)(W2 + c0 + k * 8);
    f32x4 w1 = *(const f32x4*)(W2 + c0 + k * 8 + 4);
#pragma unroll
    for (int j = 0; j < 4; j++) {
      float q0 = bfe(tt, j) + bfe(uu, j) + bfe(vv, j);
      if (q0 > 0.f) p += q0 * w0[j];
      float q1 = bfe(tt, j + 4) + bfe(uu, j + 4) + bfe(vv, j + 4);
      if (q1 > 0.f) p += q1 * w1[j];
    }
  }
  p += __shfl_xor(p, 1, 64);
  p += __shfl_xor(p, 2, 64);
  float wgt = 1.f / (1.f + __expf(-(p + b2p[0])));

  // coalesced pk scatter: per r, quad q = edge q*4+r, 16 col-lanes write
  // 16 consecutive dwords (2 bf16 each) -> one cache line per edge-row.
#pragma unroll
  for (int r = 0; r < 4; r++) {
    int src_lane = (quad * 4 + r) * 4;
    float wr = __shfl(wgt, src_lane, 64);
    int sr = __shfl(s2, src_lane, 64);
    int dr = __shfl(d2, src_lane, 64);
    const u16* yrow = yT + (size_t)sr * 128;
    u16* mrow = msgY + (size_t)dr * 128;
#pragma unroll
    for (int nt = 0; nt < 4; nt++) {
      int c = nt * 32 + col * 2;
      unsigned yv = *(const unsigned*)(yrow + c);
      pk_atomic_bf16(mrow + c, wr * bf2f((u16)(yv & 0xffff)),
                               wr * bf2f((u16)(yv >> 16)));
    }
  }
}

// ---------------------------------------------------------------------------
extern "C" void kernel_launch(void* const* d_in, const int* in_sizes, int n_in,
                              void* d_out, int out_size, void* d_ws, size_t ws_size,
                              hipStream_t stream) {
  const float* x_a      = (const float*)d_in[0];
  const float* x_b      = (const float*)d_in[1];
  const float* Wp       = (const float*)d_in[2];
  const float* bp       = (const float*)d_in[3];
  const float* Wc       = (const float*)d_in[4];
  const float* bc       = (const float*)d_in[5];
  const float* W1       = (const float*)d_in[6];
  const float* b1       = (const float*)d_in[7];
  const float* W2       = (const float*)d_in[8];
  const float* b2       = (const float*)d_in[9];
  const float* Wrel_ab  = (const float*)d_in[10];
  const float* brel_ab  = (const float*)d_in[11];
  const float* Wroot_ab = (const float*)d_in[12];
  const float* broot_ab = (const float*)d_in[13];
  const float* Wrel_ba  = (const float*)d_in[14];
  const float* brel_ba  = (const float*)d_in[15];
  const float* Wroot_ba = (const float*)d_in[16];
  const float* broot_ba = (const float*)d_in[17];
  const int*   ei_ab    = (const int*)d_in[18];
  const int*   ei_ba    = (const int*)d_in[19];

  char* ws = (char*)d_ws;
  u16* Wb        = (u16*)ws;               // 9*16384*2 B
  u16* Wp_b      = Wb + 0 * 16384;
  u16* Wc_b      = Wb + 1 * 16384;
  u16* W1a_b     = Wb + 2 * 16384;
  u16* W1b_b     = Wb + 3 * 16384;
  u16* W1c_b     = Wb + 4 * 16384;
  u16* Wrelab_b  = Wb + 5 * 16384;
  u16* Wrootab_b = Wb + 6 * 16384;
  u16* Wrelba_b  = Wb + 7 * 16384;
  u16* Wrootba_b = Wb + 8 * 16384;

  // 12.8 MB bf16 node tables
  u16* xa_bf   = (u16*)(ws + 1048576);
  u16* xb_bf   = (u16*)(ws + 13848576);
  u16* u_a     = (u16*)(ws + 26648576);
  u16* v_a     = (u16*)(ws + 39448576);
  u16* u_b     = (u16*)(ws + 52248576);
  u16* v_b     = (u16*)(ws + 65048576);
  u16* y_ab    = (u16*)(ws + 77848576);
  u16* y_ba    = (u16*)(ws + 90648576);
  u16* msgY_a  = (u16*)(ws + 103448576);   // contiguous pair, 25.6 MB total
  u16* msgY_b  = (u16*)(ws + 116248576);

  float* out_a = (float*)d_out;
  float* out_b = out_a + (size_t)N_NODES * 128;

  hipMemsetAsync(msgY_a, 0, (size_t)2 * N_NODES * 128 * sizeof(u16), stream);

  prep_weights<<<576, 256, 0, stream>>>(Wp, Wc, W1, Wrel_ab, Wroot_ab,
                                        Wrel_ba, Wroot_ba, Wb);
  cast_x<<<6250, 256, 0, stream>>>(x_a, x_b, xa_bf, xb_bf);

  encoder2<<<2 * NBLK, 256, 0, stream>>>(xa_bf, xb_bf, Wp_b, bp, Wc_b, bc,
                                         W1a_b, b1, W1b_b, u_a, v_a, u_b, v_b);
  y_gemm2<<<2 * NBLK, 256, 0, stream>>>(xa_bf, xb_bf, Wrelab_b, Wrelba_b, y_ab, y_ba);

  edge_fused<<<15625, 256, 0, stream>>>(xa_bf, xb_bf, ei_ab, ei_ba, W1c_b,
                                        u_a, v_a, u_b, v_b, y_ab, y_ba,
                                        W2, b2, msgY_a, msgY_b);

  out_gemm2<<<2 * NBLK, 256, 0, stream>>>(xa_bf, xb_bf, msgY_a, msgY_b,
                                          Wrootba_b, Wrootab_b,
                                          brel_ba, broot_ba, brel_ab, broot_ab,
                                          out_a, out_b);
}

// Round 5
// 698.637 us; speedup vs baseline: 10.0492x; 1.1054x over previous
//
#include <hip/hip_runtime.h>
#include <hip/hip_bf16.h>

typedef unsigned short u16;
typedef __attribute__((ext_vector_type(8))) short bf16x8;
typedef __attribute__((ext_vector_type(2))) short s16x2;
typedef __attribute__((ext_vector_type(4))) float f32x4;

#define N_NODES 50000
#define EDGES 500000
#define WPT 31250     // edge waves per type
#define NWAVES 3125   // node waves per type (50000/16)
#define NBLK 782      // ceil(NWAVES/4)

__device__ __forceinline__ u16 f2bf(float f) {
  return __builtin_bit_cast(u16, __float2bfloat16(f));
}
__device__ __forceinline__ float bf2f(u16 u) {
  return __builtin_bit_cast(float, ((unsigned)u) << 16);
}
__device__ __forceinline__ float bfe(bf16x8 v, int j) {
  return bf2f((u16)v[j]);
}

// packed bf16 atomic add (2 values at 4B-aligned address)
__device__ __forceinline__ void pk_atomic_bf16(u16* addr, float lo, float hi) {
#if __has_builtin(__builtin_amdgcn_global_atomic_fadd_v2bf16)
  s16x2 v;
  v[0] = (short)f2bf(lo);
  v[1] = (short)f2bf(hi);
  __builtin_amdgcn_global_atomic_fadd_v2bf16(
      (__attribute__((address_space(1))) s16x2*)addr, v);
#else
  unsigned* p = (unsigned*)addr;
  unsigned old = *p, assumed;
  do {
    assumed = old;
    float l2 = bf2f((u16)(assumed & 0xffff)) + lo;
    float h2 = bf2f((u16)(assumed >> 16)) + hi;
    unsigned nv = (unsigned)f2bf(l2) | ((unsigned)f2bf(h2) << 16);
    old = atomicCAS(p, assumed, nv);
  } while (old != assumed);
#endif
}

// ---------------------------------------------------------------------------
// weights -> bf16 tables (9 x 128x128 row-major)
// 0 Wp, 1 Wc, 2 W1a, 3 W1b, 4 W1c, 5 Wrel_ab, 6 Wroot_ab, 7 Wrel_ba, 8 Wroot_ba
// ---------------------------------------------------------------------------
__global__ __launch_bounds__(256) void prep_weights(
    const float* __restrict__ Wp, const float* __restrict__ Wc,
    const float* __restrict__ W1,
    const float* __restrict__ Wrel_ab, const float* __restrict__ Wroot_ab,
    const float* __restrict__ Wrel_ba, const float* __restrict__ Wroot_ba,
    u16* __restrict__ out)
{
  int tid = blockIdx.x * 256 + threadIdx.x;  // 9*16384
  int m = tid >> 14;
  int idx = tid & 16383;
  int r = idx >> 7;
  int c = idx & 127;
  float val;
  switch (m) {
    case 0: val = Wp[r * 128 + c]; break;
    case 1: val = Wc[r * 128 + c]; break;
    case 2: val = W1[r * 384 + c]; break;
    case 3: val = W1[r * 384 + 128 + c]; break;
    case 4: val = W1[r * 384 + 256 + c]; break;
    case 5: val = Wrel_ab[r * 128 + c]; break;
    case 6: val = Wroot_ab[r * 128 + c]; break;
    case 7: val = Wrel_ba[r * 128 + c]; break;
    default: val = Wroot_ba[r * 128 + c]; break;
  }
  out[tid] = f2bf(val);
}

// ---------------------------------------------------------------------------
// x (fp32) -> bf16 tables, 8 elems/thread
// ---------------------------------------------------------------------------
__global__ __launch_bounds__(256) void cast_x(
    const float* __restrict__ xa, const float* __restrict__ xb,
    u16* __restrict__ oa, u16* __restrict__ ob)
{
  int t = blockIdx.x * 256 + threadIdx.x;    // 1,600,000 threads
  const int HALF = (N_NODES * 128) / 8;      // 800,000
  const float* src;
  u16* dst;
  int idx;
  if (t < HALF) { src = xa; dst = oa; idx = t * 8; }
  else          { src = xb; dst = ob; idx = (t - HALF) * 8; }
  f32x4 a = *(const f32x4*)(src + idx);
  f32x4 b = *(const f32x4*)(src + idx + 4);
  bf16x8 o;
#pragma unroll
  for (int j = 0; j < 4; j++) {
    o[j]     = (short)f2bf(a[j]);
    o[j + 4] = (short)f2bf(b[j]);
  }
  *(bf16x8*)(dst + idx) = o;
}

// ---------------------------------------------------------------------------
// Fused encoder, both node sets in one dispatch (grid 2*NBLK):
//   u = lrelu(x@Wp^T+bp) @ W1a^T + b1   (b1 folded in)
//   v = lrelu(x@Wc^T+bc) @ W1b^T
// ---------------------------------------------------------------------------
__global__ __launch_bounds__(256) void encoder2(
    const u16* __restrict__ xa_bf, const u16* __restrict__ xb_bf,
    const u16* __restrict__ Wp_b, const float* __restrict__ bp,
    const u16* __restrict__ Wc_b, const float* __restrict__ bc,
    const u16* __restrict__ W1a_b, const float* __restrict__ b1,
    const u16* __restrict__ W1b_b,
    u16* __restrict__ u_a, u16* __restrict__ v_a,
    u16* __restrict__ u_b, u16* __restrict__ v_b)
{
  __shared__ u16 tile[4][2176];   // 16 x pitch 136 bf16, per wave
  int widx = threadIdx.x >> 6;
  int w = blockIdx.x * 4 + widx;         // 0 .. 2*4*NBLK-1
  int type = (w >= NBLK * 4) ? 1 : 0;
  int nw = w - type * NBLK * 4;
  if (nw >= NWAVES) nw = NWAVES - 1;     // clamp (dup work; per-wave tile, safe)
  const u16* xbf = type ? xb_bf : xa_bf;
  u16* u_out = type ? u_b : u_a;
  u16* v_out = type ? v_b : v_a;
  int row0 = nw * 16;
  int lane = threadIdx.x & 63;
  int col = lane & 15;
  int quad = lane >> 4;
  u16* tl = tile[widx];

  bf16x8 af[4];
#pragma unroll
  for (int ks = 0; ks < 4; ks++)
    af[ks] = *(const bf16x8*)(xbf + (size_t)(row0 + col) * 128 + ks * 32 + quad * 8);

  f32x4 zero = {0.f, 0.f, 0.f, 0.f};

  for (int chain = 0; chain < 2; chain++) {
    const u16* Wenc = chain ? Wc_b : Wp_b;
    const float* benc = chain ? bc : bp;
    const u16* Wmix = chain ? W1b_b : W1a_b;
    const float* bmix = chain ? nullptr : b1;
    u16* outp = chain ? v_out : u_out;

    f32x4 acc[8];
#pragma unroll
    for (int nt = 0; nt < 8; nt++) acc[nt] = zero;
#pragma unroll
    for (int ks = 0; ks < 4; ks++) {
      const u16* wp = Wenc + col * 128 + ks * 32 + quad * 8;
#pragma unroll
      for (int nt = 0; nt < 8; nt++) {
        bf16x8 bf = *(const bf16x8*)(wp + nt * 2048);
        acc[nt] = __builtin_amdgcn_mfma_f32_16x16x32_bf16(af[ks], bf, acc[nt], 0, 0, 0);
      }
    }
    // per-wave tile: in-wave lgkmcnt ordering suffices, no barrier
#pragma unroll
    for (int nt = 0; nt < 8; nt++) {
      float be = benc[nt * 16 + col];
#pragma unroll
      for (int r = 0; r < 4; r++) {
        float v = acc[nt][r] + be;
        v = v > 0.f ? v : 0.01f * v;
        tl[(quad * 4 + r) * 136 + nt * 16 + col] = f2bf(v);
      }
    }
    bf16x8 a2[4];
#pragma unroll
    for (int ks = 0; ks < 4; ks++)
      a2[ks] = *(const bf16x8*)&tl[col * 136 + ks * 32 + quad * 8];

    f32x4 acc2[8];
#pragma unroll
    for (int nt = 0; nt < 8; nt++) acc2[nt] = zero;
#pragma unroll
    for (int ks = 0; ks < 4; ks++) {
      const u16* wp = Wmix + col * 128 + ks * 32 + quad * 8;
#pragma unroll
      for (int nt = 0; nt < 8; nt++) {
        bf16x8 bf = *(const bf16x8*)(wp + nt * 2048);
        acc2[nt] = __builtin_amdgcn_mfma_f32_16x16x32_bf16(a2[ks], bf, acc2[nt], 0, 0, 0);
      }
    }
#pragma unroll
    for (int nt = 0; nt < 8; nt++) {
      float bm = bmix ? bmix[nt * 16 + col] : 0.f;
#pragma unroll
      for (int r = 0; r < 4; r++)
        outp[(size_t)(row0 + quad * 4 + r) * 128 + nt * 16 + col] = f2bf(acc2[nt][r] + bm);
    }
  }
}

// ---------------------------------------------------------------------------
// out = msgX@Wrel^T + x@Wroot^T + brel + broot  (fp32 out), both types.
// type 0: out_a (msgX_a, Wrel_ba, Wroot_ba); type 1: out_b (ab weights)
// ---------------------------------------------------------------------------
__global__ __launch_bounds__(256) void out_gemm2(
    const u16* __restrict__ xa_bf, const u16* __restrict__ xb_bf,
    const u16* __restrict__ msgX_a, const u16* __restrict__ msgX_b,
    const u16* __restrict__ Wrelba_b, const u16* __restrict__ Wrelab_b,
    const u16* __restrict__ Wrootba_b, const u16* __restrict__ Wrootab_b,
    const float* __restrict__ brel_ba, const float* __restrict__ broot_ba,
    const float* __restrict__ brel_ab, const float* __restrict__ broot_ab,
    float* __restrict__ out_a, float* __restrict__ out_b)
{
  int w = blockIdx.x * 4 + (threadIdx.x >> 6);
  int type = (w >= NBLK * 4) ? 1 : 0;
  int nw = w - type * NBLK * 4;
  if (nw >= NWAVES) return;
  const u16* xbf = type ? xb_bf : xa_bf;
  const u16* msg = type ? msgX_b : msgX_a;
  const u16* Wrel = type ? Wrelab_b : Wrelba_b;
  const u16* Wroot = type ? Wrootab_b : Wrootba_b;
  const float* brel = type ? brel_ab : brel_ba;
  const float* broot = type ? broot_ab : broot_ba;
  float* outp = type ? out_b : out_a;
  int row0 = nw * 16;
  int lane = threadIdx.x & 63;
  int col = lane & 15;
  int quad = lane >> 4;

  bf16x8 ax[4], am[4];
#pragma unroll
  for (int ks = 0; ks < 4; ks++) {
    ax[ks] = *(const bf16x8*)(xbf + (size_t)(row0 + col) * 128 + ks * 32 + quad * 8);
    am[ks] = *(const bf16x8*)(msg + (size_t)(row0 + col) * 128 + ks * 32 + quad * 8);
  }

  f32x4 zero = {0.f, 0.f, 0.f, 0.f};
  f32x4 acc[8];
#pragma unroll
  for (int nt = 0; nt < 8; nt++) acc[nt] = zero;
#pragma unroll
  for (int ks = 0; ks < 4; ks++) {
    const u16* wp1 = Wrel + col * 128 + ks * 32 + quad * 8;
    const u16* wp2 = Wroot + col * 128 + ks * 32 + quad * 8;
#pragma unroll
    for (int nt = 0; nt < 8; nt++) {
      bf16x8 b1f = *(const bf16x8*)(wp1 + nt * 2048);
      acc[nt] = __builtin_amdgcn_mfma_f32_16x16x32_bf16(am[ks], b1f, acc[nt], 0, 0, 0);
      bf16x8 b2f = *(const bf16x8*)(wp2 + nt * 2048);
      acc[nt] = __builtin_amdgcn_mfma_f32_16x16x32_bf16(ax[ks], b2f, acc[nt], 0, 0, 0);
    }
  }
#pragma unroll
  for (int nt = 0; nt < 8; nt++) {
    int c = nt * 16 + col;
    float b = brel[c] + broot[c];
#pragma unroll
    for (int r = 0; r < 4; r++)
      outp[(size_t)(row0 + quad * 4 + r) * 128 + c] = acc[nt][r] + b;
  }
}

// ---------------------------------------------------------------------------
// Merged edge kernel, both types. Wave = 16 edges. No __syncthreads (tiles
// are per-wave; in-wave LDS ordering is by lgkmcnt).
// Phase 1: bf16 gathers -> |par-cld| A-frags -> 32 MFMAs (t = d@W1c^T)
// t -> LDS (C-layout -> edge-major), epilogue computes w (relu-dot-sigmoid).
// Then xs frags (still in regs) -> same LDS tile -> coalesced pk_add_bf16
// scatter of w * x_src into msgX (16 atomic insts/wave, no y gather).
// ---------------------------------------------------------------------------
__global__ __launch_bounds__(256) void edge_fused(
    const u16* __restrict__ xa_bf, const u16* __restrict__ xb_bf,
    const int* __restrict__ ei_ab, const int* __restrict__ ei_ba,
    const u16* __restrict__ W1c,
    const u16* __restrict__ u_a, const u16* __restrict__ v_a,
    const u16* __restrict__ u_b, const u16* __restrict__ v_b,
    const float* __restrict__ W2, const float* __restrict__ b2p,
    u16* __restrict__ msgX_a, u16* __restrict__ msgX_b)
{
  __shared__ u16 tld[4][2176];   // 16 x pitch 136 bf16, per wave (17.4 KB)
  int widx = threadIdx.x >> 6;
  int w = blockIdx.x * 4 + widx;   // 0..62499
  int type = (w >= WPT) ? 1 : 0;
  int e0 = (w - type * WPT) * 16;
  const u16* xs = type ? xb_bf : xa_bf;
  const u16* xd = type ? xa_bf : xb_bf;
  const int* ei = type ? ei_ba : ei_ab;
  const u16* uT = type ? u_b : u_a;
  const u16* vT = type ? v_a : v_b;
  u16* msgX     = type ? msgX_a : msgX_b;

  int lane = threadIdx.x & 63;
  int col = lane & 15;
  int quad = lane >> 4;

  int em = e0 + col;
  int si = ei[em];
  int di = ei[EDGES + em];

  bf16x8 af[4];   // xs fragments — kept live for the scatter
  bf16x8 df[4];   // |par - cld|
#pragma unroll
  for (int ks = 0; ks < 4; ks++) {
    af[ks] = *(const bf16x8*)(xs + (size_t)si * 128 + ks * 32 + quad * 8);
    bf16x8 d8 = *(const bf16x8*)(xd + (size_t)di * 128 + ks * 32 + quad * 8);
#pragma unroll
    for (int j = 0; j < 8; j++)
      df[ks][j] = (short)f2bf(__builtin_fabsf(bfe(af[ks], j) - bfe(d8, j)));
  }

  f32x4 zero = {0.f, 0.f, 0.f, 0.f};
  f32x4 acc[8];
#pragma unroll
  for (int nt = 0; nt < 8; nt++) acc[nt] = zero;
#pragma unroll
  for (int ks = 0; ks < 4; ks++) {
    const u16* wp = W1c + col * 128 + ks * 32 + quad * 8;
#pragma unroll
    for (int nt = 0; nt < 8; nt++) {
      bf16x8 bf = *(const bf16x8*)(wp + nt * 2048);
      acc[nt] = __builtin_amdgcn_mfma_f32_16x16x32_bf16(df[ks], bf, acc[nt], 0, 0, 0);
    }
  }

  u16* tl = tld[widx];
#pragma unroll
  for (int nt = 0; nt < 8; nt++)
#pragma unroll
    for (int r = 0; r < 4; r++)
      tl[(quad * 4 + r) * 136 + nt * 16 + col] = f2bf(acc[nt][r]);

  // edge-major epilogue: lane = (edge = lane>>2, strip = (lane&3)*32)
  int e = e0 + (lane >> 2);
  int s2 = ei[e];
  int d2 = ei[EDGES + e];
  int c0 = (lane & 3) * 32;
  const u16* trow = &tl[(lane >> 2) * 136 + c0];
  const u16* urow = uT + (size_t)s2 * 128 + c0;
  const u16* vrow = vT + (size_t)d2 * 128 + c0;

  float p = 0.f;
#pragma unroll
  for (int k = 0; k < 4; k++) {
    bf16x8 tt = *(const bf16x8*)(trow + k * 8);
    bf16x8 uu = *(const bf16x8*)(urow + k * 8);
    bf16x8 vv = *(const bf16x8*)(vrow + k * 8);
    f32x4 w0 = *(const f32x4*)(W2 + c0 + k * 8);
    f32x4 w1 = *(const f32x4*)(W2 + c0 + k * 8 + 4);
#pragma unroll
    for (int j = 0; j < 4; j++) {
      float q0 = bfe(tt, j) + bfe(uu, j) + bfe(vv, j);
      if (q0 > 0.f) p += q0 * w0[j];
      float q1 = bfe(tt, j + 4) + bfe(uu, j + 4) + bfe(vv, j + 4);
      if (q1 > 0.f) p += q1 * w1[j];
    }
  }
  p += __shfl_xor(p, 1, 64);
  p += __shfl_xor(p, 2, 64);
  float wgt = 1.f / (1.f + __expf(-(p + b2p[0])));

  // xs frags -> same per-wave tile (t reads above are in-wave ordered)
#pragma unroll
  for (int ks = 0; ks < 4; ks++)
    *(bf16x8*)&tl[col * 136 + ks * 32 + quad * 8] = af[ks];

  // coalesced pk scatter: per r, quad q = edge q*4+r, 16 col-lanes write
  // 16 consecutive dwords (2 bf16 each) = one cache line per edge-row.
#pragma unroll
  for (int r = 0; r < 4; r++) {
    int src_lane = (quad * 4 + r) * 4;
    float wr = __shfl(wgt, src_lane, 64);
    int dr = __shfl(d2, src_lane, 64);
    u16* mrow = msgX + (size_t)dr * 128;
    const u16* xrow = &tl[(quad * 4 + r) * 136];
#pragma unroll
    for (int nt = 0; nt < 4; nt++) {
      int c = nt * 32 + col * 2;
      unsigned xv = *(const unsigned*)(xrow + c);
      pk_atomic_bf16(mrow + c, wr * bf2f((u16)(xv & 0xffff)),
                               wr * bf2f((u16)(xv >> 16)));
    }
  }
}

// ---------------------------------------------------------------------------
extern "C" void kernel_launch(void* const* d_in, const int* in_sizes, int n_in,
                              void* d_out, int out_size, void* d_ws, size_t ws_size,
                              hipStream_t stream) {
  const float* x_a      = (const float*)d_in[0];
  const float* x_b      = (const float*)d_in[1];
  const float* Wp       = (const float*)d_in[2];
  const float* bp       = (const float*)d_in[3];
  const float* Wc       = (const float*)d_in[4];
  const float* bc       = (const float*)d_in[5];
  const float* W1       = (const float*)d_in[6];
  const float* b1       = (const float*)d_in[7];
  const float* W2       = (const float*)d_in[8];
  const float* b2       = (const float*)d_in[9];
  const float* Wrel_ab  = (const float*)d_in[10];
  const float* brel_ab  = (const float*)d_in[11];
  const float* Wroot_ab = (const float*)d_in[12];
  const float* broot_ab = (const float*)d_in[13];
  const float* Wrel_ba  = (const float*)d_in[14];
  const float* brel_ba  = (const float*)d_in[15];
  const float* Wroot_ba = (const float*)d_in[16];
  const float* broot_ba = (const float*)d_in[17];
  const int*   ei_ab    = (const int*)d_in[18];
  const int*   ei_ba    = (const int*)d_in[19];

  char* ws = (char*)d_ws;
  u16* Wb        = (u16*)ws;               // 9*16384*2 B
  u16* Wp_b      = Wb + 0 * 16384;
  u16* Wc_b      = Wb + 1 * 16384;
  u16* W1a_b     = Wb + 2 * 16384;
  u16* W1b_b     = Wb + 3 * 16384;
  u16* W1c_b     = Wb + 4 * 16384;
  u16* Wrelab_b  = Wb + 5 * 16384;
  u16* Wrootab_b = Wb + 6 * 16384;
  u16* Wrelba_b  = Wb + 7 * 16384;
  u16* Wrootba_b = Wb + 8 * 16384;

  // 12.8 MB bf16 node tables
  u16* xa_bf   = (u16*)(ws + 1048576);
  u16* xb_bf   = (u16*)(ws + 13848576);
  u16* u_a     = (u16*)(ws + 26648576);
  u16* v_a     = (u16*)(ws + 39448576);
  u16* u_b     = (u16*)(ws + 52248576);
  u16* v_b     = (u16*)(ws + 65048576);
  u16* msgX_a  = (u16*)(ws + 77848576);    // contiguous pair, 25.6 MB total
  u16* msgX_b  = (u16*)(ws + 90648576);

  float* out_a = (float*)d_out;
  float* out_b = out_a + (size_t)N_NODES * 128;

  hipMemsetAsync(msgX_a, 0, (size_t)2 * N_NODES * 128 * sizeof(u16), stream);

  prep_weights<<<576, 256, 0, stream>>>(Wp, Wc, W1, Wrel_ab, Wroot_ab,
                                        Wrel_ba, Wroot_ba, Wb);
  cast_x<<<6250, 256, 0, stream>>>(x_a, x_b, xa_bf, xb_bf);

  encoder2<<<2 * NBLK, 256, 0, stream>>>(xa_bf, xb_bf, Wp_b, bp, Wc_b, bc,
                                         W1a_b, b1, W1b_b, u_a, v_a, u_b, v_b);

  edge_fused<<<15625, 256, 0, stream>>>(xa_bf, xb_bf, ei_ab, ei_ba, W1c_b,
                                        u_a, v_a, u_b, v_b,
                                        W2, b2, msgX_a, msgX_b);

  out_gemm2<<<2 * NBLK, 256, 0, stream>>>(xa_bf, xb_bf, msgX_a, msgX_b,
                                          Wrelba_b, Wrelab_b,
                                          Wrootba_b, Wrootab_b,
                                          brel_ba, broot_ba, brel_ab, broot_ab,
                                          out_a, out_b);
}